// Round 7
// baseline (126.399 us; speedup 1.0000x reference)
//
#include <hip/hip_runtime.h>
#include <math.h>

#define MM 4
#define BB 128
#define CC 10
#define KK 32
#define FF 512
#define HH 512
#define NP 320            // C*K rows per model
#define OUTW 5120         // F*C

using bf16x8 = __attribute__((ext_vector_type(8))) short;
using f32x4  = __attribute__((ext_vector_type(4))) float;

__device__ __forceinline__ unsigned short f2bf(float f) {
    unsigned int u = __float_as_uint(f);
    u += 0x7FFFu + ((u >> 16) & 1u);          // round-to-nearest-even
    return (unsigned short)(u >> 16);
}

// ---------------- unified MFMA GEMM tile, depth-2 pipelined ----------------
// Waves WRxWC, per-wave fragments IxJ. TR=WR*I*16, TC=WC*J*16 (TC must be 64).
// B is ALWAYS staged directly from f32 k-major W[k][NCOLS] (coalesced).
// ASRC 0: bf16 A[row][512];  ASRC 2: f32 noise[row%NP][512]*r1 + onehot tail.
// EPI 0: bf16( relu(acc*s+bias) * auxr )                      (fc1 -> A2)
// EPI 1: psum natural write + pn_part slot                    (fc2)
// EPI 2: LDS z-tile, per-(row,class) zn/cr, slot write        (z-GEMM)
template<int EPI, int ASRC, int WR, int WC, int I, int J,
         int KSTEPS, int KREALB, int RPM, int NCOLS>
__device__ __forceinline__ void gemm_tile(
    const int bx, const int by,
    const unsigned short* __restrict__ Abf, const float* __restrict__ Af32,
    const float* __restrict__ ascale, const float* __restrict__ Bf32,
    const float* __restrict__ s, const float* __restrict__ bias,
    const float* __restrict__ auxr, void* __restrict__ outv,
    float* __restrict__ auxw, unsigned short* smem)
{
    constexpr int TR = WR * I * 16;
    constexpr int TC = WC * J * 16;
    static_assert(TC == 64, "direct B staging needs TC==64");
    constexpr int BUFE = (TR + TC) * 32;
    constexpr int NUA = (TR * 4 + 255) / 256;

    const int t = threadIdx.x;
    const int lane = t & 63;
    const int w = t >> 6;
    const int wr = w / WC, wc = w % WC;
    const int l15 = lane & 15, l4 = lane >> 4;
    const int rowT = by * TR, colT = bx * TC;
    const int m = rowT / RPM;

    // ---- A staging setup ----
    int stA[NUA];
    const unsigned short* gA[NUA];
    const float* gAf = nullptr;
    const float* scp = nullptr;
    int cn = 0, ag2 = 0;
#pragma unroll
    for (int u = 0; u < NUA; ++u) {
        const int eu = t + u * 256;
        const int asrow = eu >> 2, ag = eu & 3;
        stA[u] = asrow * 32 + ((ag ^ ((asrow >> 1) & 3)) * 8);
        gA[u] = nullptr;
        if constexpr (ASRC == 0) {
            if (eu < TR * 4) gA[u] = Abf + (size_t)(rowT + asrow) * 512 + ag * 8;
        }
    }
    if constexpr (ASRC == 2) {
        static_assert(TR == 64, "ASRC2 needs TR==64");
        const int asrow = t >> 2; ag2 = t & 3;
        gAf = Af32 + (size_t)((rowT % NP) + asrow) * 512 + ag2 * 8;
        scp = ascale + (size_t)m * 522 + ag2 * 8;
        cn = ((rowT % NP) + asrow) >> 5;
    }
    // ---- B staging setup ----
    const int bcol = t & 63, bkg = t >> 6;
    const int stB = bcol * 32 + ((bkg ^ ((bcol >> 1) & 3)) * 8);

    int offA[I], offB[J];
#pragma unroll
    for (int i = 0; i < I; ++i) {
        const int rA = wr * (I * 16) + i * 16 + l15;
        offA[i] = rA * 32 + ((l4 ^ ((rA >> 1) & 3)) * 8);
    }
#pragma unroll
    for (int j = 0; j < J; ++j) {
        const int rB = wc * (J * 16) + j * 16 + l15;
        offB[j] = rB * 32 + ((l4 ^ ((rB >> 1) & 3)) * 8);
    }

    f32x4 acc[I][J];
#pragma unroll
    for (int i = 0; i < I; ++i)
#pragma unroll
        for (int j = 0; j < J; ++j) acc[i][j] = (f32x4){0.f, 0.f, 0.f, 0.f};

    // two register prefetch sets (all indices literal -> no scratch)
    uint4 ra[2][NUA];
    float4 nf0[2], nf1[2], ns0[2], ns1[2];
    float rbf[2][8];

#define FETCH(KS, SEL)                                                         \
    {                                                                          \
        const int k0_ = (KS) * 32;                                             \
        if constexpr (ASRC == 0) {                                             \
            _Pragma("unroll")                                                  \
            for (int u = 0; u < NUA; ++u)                                      \
                if ((t + u * 256) < TR * 4)                                    \
                    ra[SEL][u] = *(const uint4*)(gA[u] + k0_);                 \
        } else {                                                               \
            if (k0_ < 512) {                                                   \
                nf0[SEL] = *(const float4*)(gAf + k0_);                        \
                nf1[SEL] = *(const float4*)(gAf + k0_ + 4);                    \
                ns0[SEL] = *(const float4*)(scp + k0_);                        \
                ns1[SEL] = *(const float4*)(scp + k0_ + 4);                    \
            }                                                                  \
        }                                                                      \
        _Pragma("unroll")                                                      \
        for (int q = 0; q < 8; ++q) {                                          \
            const int gk = k0_ + bkg * 8 + q;                                  \
            rbf[SEL][q] = (gk < KREALB)                                        \
                ? Bf32[(size_t)gk * NCOLS + colT + bcol] : 0.f;                \
        }                                                                      \
    }

#define WRITE(KS, SEL, BUF)                                                    \
    {                                                                          \
        const int k0_ = (KS) * 32;                                             \
        unsigned short* As_ = smem + (BUF) * BUFE;                             \
        unsigned short* Bs_ = As_ + TR * 32;                                   \
        if constexpr (ASRC == 0) {                                             \
            _Pragma("unroll")                                                  \
            for (int u = 0; u < NUA; ++u)                                      \
                if ((t + u * 256) < TR * 4) *(uint4*)(As_ + stA[u]) = ra[SEL][u]; \
        } else {                                                               \
            union { unsigned short us[8]; uint4 q4; } o;                       \
            if (k0_ < 512) {                                                   \
                float vv[8] = {nf0[SEL].x, nf0[SEL].y, nf0[SEL].z, nf0[SEL].w, \
                               nf1[SEL].x, nf1[SEL].y, nf1[SEL].z, nf1[SEL].w};\
                float ss[8] = {ns0[SEL].x, ns0[SEL].y, ns0[SEL].z, ns0[SEL].w, \
                               ns1[SEL].x, ns1[SEL].y, ns1[SEL].z, ns1[SEL].w};\
                _Pragma("unroll")                                              \
                for (int q = 0; q < 8; ++q) o.us[q] = f2bf(vv[q] * ss[q]);     \
            } else {                                                           \
                _Pragma("unroll")                                              \
                for (int q = 0; q < 8; ++q) {                                  \
                    const int gk = k0_ + ag2 * 8 + q;                          \
                    float v = (gk < 522 && (gk - 512) == cn)                   \
                        ? ascale[(size_t)m * 522 + gk] : 0.f;                  \
                    o.us[q] = f2bf(v);                                         \
                }                                                              \
            }                                                                  \
            *(uint4*)(As_ + stA[0]) = o.q4;                                    \
        }                                                                      \
        {                                                                      \
            union { unsigned short us[8]; uint4 q4; } ob;                      \
            _Pragma("unroll")                                                  \
            for (int q = 0; q < 8; ++q) ob.us[q] = f2bf(rbf[SEL][q]);          \
            *(uint4*)(Bs_ + stB) = ob.q4;                                      \
        }                                                                      \
    }

#define MFMA_STEP(BUF)                                                         \
    {                                                                          \
        const unsigned short* As_ = smem + (BUF) * BUFE;                       \
        const unsigned short* Bs_ = As_ + TR * 32;                             \
        bf16x8 af[I], bfv[J];                                                  \
        _Pragma("unroll")                                                      \
        for (int i = 0; i < I; ++i) af[i] = *(const bf16x8*)(As_ + offA[i]);   \
        _Pragma("unroll")                                                      \
        for (int j = 0; j < J; ++j) bfv[j] = *(const bf16x8*)(Bs_ + offB[j]);  \
        _Pragma("unroll")                                                      \
        for (int i = 0; i < I; ++i)                                            \
            _Pragma("unroll")                                                  \
            for (int j = 0; j < J; ++j)                                        \
                acc[i][j] = __builtin_amdgcn_mfma_f32_16x16x32_bf16(           \
                    af[i], bfv[j], acc[i][j], 0, 0, 0);                        \
    }

    // prologue: F0 staged, F1 in flight
    FETCH(0, 0);
    WRITE(0, 0, 0);
    FETCH(1, 1);
    __syncthreads();

#pragma unroll 1
    for (int ks2 = 0; ks2 < KSTEPS; ks2 += 2) {
        if (ks2 + 2 < KSTEPS) FETCH(ks2 + 2, 0);
        MFMA_STEP(0);
        if (ks2 + 1 < KSTEPS) {
            WRITE(ks2 + 1, 1, 1);
            __syncthreads();
            if (ks2 + 3 < KSTEPS) FETCH(ks2 + 3, 1);
            MFMA_STEP(1);
            if (ks2 + 2 < KSTEPS) {
                WRITE(ks2 + 2, 0, 0);
                __syncthreads();
            }
        }
    }
#undef FETCH
#undef WRITE
#undef MFMA_STEP

    if constexpr (EPI == 0) {
#pragma unroll
        for (int j = 0; j < J; ++j) {
            const int col = colT + wc * (J * 16) + j * 16 + l15;
            const float sv = s[(size_t)m * NCOLS + col];
            const float bv = bias[(size_t)m * NCOLS + col];
            const float rv = auxr[(size_t)m * NCOLS + col];
#pragma unroll
            for (int i = 0; i < I; ++i)
#pragma unroll
                for (int ir = 0; ir < 4; ++ir) {
                    const int row = rowT + wr * (I * 16) + i * 16 + l4 * 4 + ir;
                    float v = fmaxf(acc[i][j][ir] * sv + bv, 0.f) * rv;
                    ((unsigned short*)outv)[(size_t)row * NCOLS + col] = f2bf(v);
                }
        }
    } else if constexpr (EPI == 1) {
        // block rows = one (m,c) class group (TR==32); psum in NATURAL (f,c) order
        static_assert(WR == 1 && I == 2 && J == 1, "EPI1 geometry");
        const int mq = rowT / NP;
        const int c = (rowT % NP) / KK;
        const int mc = mq * CC + c;
        const int col = colT + wc * 16 + l15;
        const float sv = s[(size_t)mq * NCOLS + col];
        const float bv = bias[(size_t)mq * NCOLS + col];
        float cs = 0.f, sq = 0.f;
#pragma unroll
        for (int i = 0; i < I; ++i)
#pragma unroll
            for (int ir = 0; ir < 4; ++ir) {
                float v = acc[i][0][ir] * sv + bv;
                cs += v;
                sq += v * v;
            }
        cs += __shfl_xor(cs, 16, 64);
        cs += __shfl_xor(cs, 32, 64);
        if (l4 == 0)
            ((float*)outv)[(size_t)mq * (CC * NCOLS) + (size_t)col * CC + c] = cs;
#pragma unroll
        for (int off = 1; off < 64; off <<= 1) sq += __shfl_xor(sq, off, 64);
        if (lane == 0) auxw[mc * 32 + bx * 4 + w] = sq;
    } else {
        // EPI 2: natural-order class reduction via LDS z-tile
        static_assert(WR == 2 && WC == 2 && J == 2, "EPI2 geometry");
        __syncthreads();                       // staging LDS now dead
        float* zt = (float*)smem;              // [TR][66]
        float* ps = zt + TR * 66;              // [64] psum tile
        float sv[J];
#pragma unroll
        for (int j = 0; j < J; ++j)
            sv[j] = s[(size_t)m * NCOLS + colT + wc * (J * 16) + j * 16 + l15];
#pragma unroll
        for (int i = 0; i < I; ++i)
#pragma unroll
            for (int j = 0; j < J; ++j)
#pragma unroll
                for (int ir = 0; ir < 4; ++ir) {
                    const int row_l = wr * (I * 16) + i * 16 + l4 * 4 + ir;
                    const int col_l = wc * (J * 16) + j * 16 + l15;
                    zt[row_l * 66 + col_l] = acc[i][j][ir] * sv[j];
                }
        if (t < 64) ps[t] = bias[(size_t)m * NCOLS + colT + t];
        __syncthreads();
        const int c0 = colT % 10;
#pragma unroll 1
        for (int p = t; p < TR * 10; p += 256) {
            const int row_l = p / 10, c = p % 10;
            int cl = c - c0; if (cl < 0) cl += 10;
            float zn = 0.f, cr = 0.f;
            for (; cl < 64; cl += 10) {
                const float v = zt[row_l * 66 + cl];
                zn += v * v;
                cr += v * ps[cl];
            }
            float2 o = {zn, cr};
            *(float2*)((float*)outv +
                ((size_t)bx * 5120 + (size_t)(rowT + row_l) * 10 + c) * 2) = o;
        }
    }
}

// ====== K1: fc1 GEMM (direct from noise/W1) + xr build + ticket reset ======
__global__ __launch_bounds__(256) void k_phase1(
    const float* __restrict__ noise, const float* __restrict__ r1,
    const float* __restrict__ W1, const float* __restrict__ s1,
    const float* __restrict__ b1, const float* __restrict__ r2,
    const float* __restrict__ x, const float* __restrict__ r_lw,
    unsigned short* __restrict__ A2, unsigned short* __restrict__ xr,
    unsigned int* __restrict__ ticket)
{
    __shared__ __align__(16) unsigned short smem[8192];   // 16 KiB
    const int b = blockIdx.x;
    const int t = threadIdx.x;
    if (b < 160) {
        gemm_tile<0, 2, 2, 2, 2, 2, 17, 522, NP, HH>(
            b % 8, b / 8, nullptr, noise, r1, W1,
            s1, b1, r2, (void*)A2, nullptr, smem);
    } else {
        const int id = (b - 160) * 256 + t;               // 32768 exact
        const int row = id >> 6, g = id & 63;
        const int mq = row >> 7;
        const float* xp = x + (size_t)row * 512 + g * 8;
        const float* rp = r_lw + (size_t)mq * 512 + g * 8;
        union { unsigned short us[8]; uint4 v; } o;
#pragma unroll
        for (int q = 0; q < 8; ++q) o.us[q] = f2bf(xp[q] * rp[q]);
        *(uint4*)(xr + (size_t)row * 512 + g * 8) = o.v;
        if (b == 287 && t == 0) *ticket = 0u;
    }
}

// ====== K2: fc2 GEMM (direct W2) + fused psum(natural)/pn_part ======
__global__ __launch_bounds__(256) void k_phase2(
    const unsigned short* __restrict__ A2, const float* __restrict__ W2,
    const float* __restrict__ s2, const float* __restrict__ b2,
    float* __restrict__ psum, float* __restrict__ pn_part)
{
    __shared__ __align__(16) unsigned short smem[6144];   // 12 KiB
    gemm_tile<1, 0, 1, 4, 2, 1, 16, 512, NP, FF>(
        blockIdx.x, blockIdx.y, A2, nullptr, nullptr, W2,
        s2, b2, nullptr, (void*)psum, pn_part, smem);
}

// ====== K3: z GEMM (direct f32 W_lw) + class reduce + fused out-tail ======
__global__ __launch_bounds__(256) void k_phase3(
    const unsigned short* __restrict__ xr, const float* __restrict__ W_lw,
    const float* __restrict__ s_lw, const float* __restrict__ psum,
    float* __restrict__ dist_part, const float* __restrict__ pn_part,
    unsigned int* __restrict__ ticket, float* __restrict__ out)
{
    __shared__ __align__(16) unsigned short smem[17024];  // 34,048 B
    const int blk = blockIdx.x;
    const int t = threadIdx.x;
    if (blk < 320) {
        gemm_tile<2, 0, 2, 2, 4, 2, 16, 512, BB, OUTW>(
            blk % 80, blk / 80, xr, nullptr, nullptr, W_lw,
            s_lw, psum, nullptr, (void*)dist_part, nullptr, smem);
        __syncthreads();
        if (t == 0) {
            __threadfence();
            __hip_atomic_fetch_add(ticket, 1u, __ATOMIC_RELEASE,
                                   __HIP_MEMORY_SCOPE_AGENT);
        }
    } else {
        // 20 tail blocks: wait for all 320 GEMM blocks, then reduce + exp
        if (t == 0) {
            while (__hip_atomic_load(ticket, __ATOMIC_ACQUIRE,
                                     __HIP_MEMORY_SCOPE_AGENT) < 320u)
                __builtin_amdgcn_s_sleep(8);
        }
        __syncthreads();
        __threadfence();
        const int id = (blk - 320) * 256 + t;             // 5120 exact
        const int c = id % 10;
        const int mc = ((id / 10) >> 7) * 10 + c;
        float zn = 0.f, cr = 0.f;
#pragma unroll 1
        for (int q = 0; q < 80; ++q) {
            const float* dp = dist_part + ((size_t)q * 5120 + id) * 2;
            zn += __hip_atomic_load(dp, __ATOMIC_RELAXED, __HIP_MEMORY_SCOPE_AGENT);
            cr += __hip_atomic_load(dp + 1, __ATOMIC_RELAXED, __HIP_MEMORY_SCOPE_AGENT);
        }
        float pnv = 0.f;
#pragma unroll
        for (int q = 0; q < 32; ++q) pnv += pn_part[mc * 32 + q];
        const float inv = 1.f / (2.f * (float)KK * (float)FF);
        out[id] = expf(-((float)KK * zn - 2.f * cr + pnv) * inv);
    }
}

extern "C" void kernel_launch(void* const* d_in, const int* in_sizes, int n_in,
                              void* d_out, int out_size, void* d_ws, size_t ws_size,
                              hipStream_t stream) {
    const float* x     = (const float*)d_in[0];
    const float* noise = (const float*)d_in[1];
    const float* W_lw  = (const float*)d_in[2];
    const float* r_lw  = (const float*)d_in[3];
    const float* s_lw  = (const float*)d_in[4];
    const float* W1    = (const float*)d_in[5];
    const float* r1    = (const float*)d_in[6];
    const float* s1    = (const float*)d_in[7];
    const float* b1    = (const float*)d_in[8];
    const float* W2    = (const float*)d_in[9];
    const float* r2    = (const float*)d_in[10];
    const float* s2    = (const float*)d_in[11];
    const float* b2    = (const float*)d_in[12];
    float* out = (float*)d_out;

    char* base = (char*)d_ws;
    float* psum          = (float*)(base + 0);                 //    81,920 B
    float* pn_part       = (float*)(base + 81920);             //     5,120 B
    float* dist_part     = (float*)(base + 87040);             // 3,276,800 B
    unsigned int* ticket = (unsigned int*)(base + 3363840);    //       256 B
    unsigned short* A2   = (unsigned short*)(base + 3364096);  // 1,310,720 B
    unsigned short* xr   = (unsigned short*)(base + 4674816);  //   524,288 B

    k_phase1<<<288, 256, 0, stream>>>(noise, r1, W1, s1, b1, r2, x, r_lw,
                                      A2, xr, ticket);
    k_phase2<<<dim3(8, 40), 256, 0, stream>>>(A2, W2, s2, b2, psum, pn_part);
    k_phase3<<<340, 256, 0, stream>>>(xr, W_lw, s_lw, psum, dist_part,
                                      pn_part, ticket, out);
}